// Round 1
// baseline (1744.181 us; speedup 1.0000x reference)
//
#include <hip/hip_runtime.h>
#include <hip/hip_bf16.h>

#define B_ROWS 8192
#define IN_DIM 1024
#define H_DIM  1024
#define WRANK  256
#define UR0    64
#define UR1    32
#define NG     2
#define HGD    512

// ---------------- generic tiled fp32 GEMM (correctness-first) ----------------
// C[M,N] = A[M,K] @ Bw[K,N], all row-major with given leading dims.
template<int BM, int BN, int BK, int TM, int TN>
__global__ __launch_bounds__((BM/TM)*(BN/TN))
void sgemm_kernel(const float* __restrict__ A, int lda,
                  const float* __restrict__ Bw, int ldb,
                  float* __restrict__ C, int ldc,
                  int M, int N, int K)
{
    constexpr int NT = (BM/TM)*(BN/TN);
    __shared__ float As[BK][BM+1];
    __shared__ float Bs[BK][BN+1];
    const int tid  = threadIdx.x;
    const int tcol = tid % (BN/TN);
    const int trow = tid / (BN/TN);
    const int m0 = blockIdx.y * BM;
    const int n0 = blockIdx.x * BN;

    float acc[TM][TN];
    #pragma unroll
    for (int i = 0; i < TM; ++i)
        #pragma unroll
        for (int j = 0; j < TN; ++j) acc[i][j] = 0.f;

    for (int k0 = 0; k0 < K; k0 += BK) {
        // stage A tile (BM x BK), transposed into LDS
        for (int idx = tid; idx < BM*BK; idx += NT) {
            int m = idx / BK, k = idx % BK;
            float v = 0.f;
            if (m0 + m < M) v = A[(size_t)(m0+m)*lda + k0 + k];
            As[k][m] = v;
        }
        // stage B tile (BK x BN)
        for (int idx = tid; idx < BK*BN; idx += NT) {
            int k = idx / BN, n = idx % BN;
            float v = 0.f;
            if (n0 + n < N) v = Bw[(size_t)(k0+k)*ldb + n0 + n];
            Bs[k][n] = v;
        }
        __syncthreads();
        #pragma unroll
        for (int kk = 0; kk < BK; ++kk) {
            float ra[TM], rb[TN];
            #pragma unroll
            for (int i = 0; i < TM; ++i) ra[i] = As[kk][trow*TM + i];
            #pragma unroll
            for (int j = 0; j < TN; ++j) rb[j] = Bs[kk][tcol*TN + j];
            #pragma unroll
            for (int i = 0; i < TM; ++i)
                #pragma unroll
                for (int j = 0; j < TN; ++j)
                    acc[i][j] += ra[i] * rb[j];
        }
        __syncthreads();
    }
    #pragma unroll
    for (int i = 0; i < TM; ++i) {
        int m = m0 + trow*TM + i;
        if (m >= M) continue;
        #pragma unroll
        for (int j = 0; j < TN; ++j) {
            int n = n0 + tcol*TN + j;
            if (n < N) C[(size_t)m*ldc + n] = acc[i][j];
        }
    }
}

// ---------------- fused gate GEMM + LSTM epilogue ----------------
// For output tile (b-block x j-block), accumulate over concatenated K=352:
//   k in [0,256)   : xw[b,k]        * Wq[k, j]
//   k in [256,320) : tU[b,g,k-256]  * Uq[g, k-256, j']
//   k in [320,352) : tUU[b,g,k-320] * UUq[g, k-320, j']
// then gates + c/h epilogue.
#define BM2 64
#define BN2 64
#define BK2 32
#define TM2 4
#define TN2 4
#define KTOT (WRANK + UR0 + UR1)   // 352

__global__ __launch_bounds__(256)
void lstm_gate_kernel(const float* __restrict__ xw,    // [B][256]
                      const float* __restrict__ tU,    // [B][128]  (g*64 + r)
                      const float* __restrict__ tUU,   // [B][64]   (g*32 + r)
                      const float* __restrict__ W1, const float* __restrict__ W2,
                      const float* __restrict__ W3, const float* __restrict__ W4,
                      const float* __restrict__ U1, const float* __restrict__ U2,
                      const float* __restrict__ U3, const float* __restrict__ U4,
                      const float* __restrict__ UU1, const float* __restrict__ UU2,
                      const float* __restrict__ UU3, const float* __restrict__ UU4,
                      const float* __restrict__ bias_i, const float* __restrict__ bias_f,
                      const float* __restrict__ bias_o, const float* __restrict__ bias_c,
                      const float* __restrict__ cin,
                      float* __restrict__ c_out, float* __restrict__ h_out)
{
    __shared__ float As[BK2][BM2+1];
    __shared__ float Bs[4][BK2][BN2+1];

    const int tid  = threadIdx.x;
    const int m0   = blockIdx.y * BM2;
    const int n0   = blockIdx.x * BN2;     // 64-col tiles never cross the group boundary (512 % 64 == 0)
    const int g    = n0 / HGD;
    const int jb   = n0 - g*HGD;           // column base within group
    const int trow = tid / (BN2/TN2);      // 0..15
    const int tcol = tid % (BN2/TN2);      // 0..15

    const float* Wm[4]  = {W1, W2, W3, W4};
    const float* Um[4]  = {U1, U2, U3, U4};
    const float* UUm[4] = {UU1, UU2, UU3, UU4};

    float acc[4][TM2][TN2];
    #pragma unroll
    for (int q = 0; q < 4; ++q)
        #pragma unroll
        for (int i = 0; i < TM2; ++i)
            #pragma unroll
            for (int j = 0; j < TN2; ++j) acc[q][i][j] = 0.f;

    for (int k0 = 0; k0 < KTOT; k0 += BK2) {
        // stage A (64 x 32) from concatenated K space
        for (int idx = tid; idx < BM2*BK2; idx += 256) {
            int m = idx / BK2, kk = idx % BK2;
            int k = k0 + kk;
            int b = m0 + m;
            float v;
            if (k < WRANK)              v = xw[(size_t)b*WRANK + k];
            else if (k < WRANK + UR0)   v = tU[(size_t)b*(NG*UR0) + g*UR0 + (k - WRANK)];
            else                        v = tUU[(size_t)b*(NG*UR1) + g*UR1 + (k - WRANK - UR0)];
            As[kk][m] = v;
        }
        // stage B for 4 gates (each 32 x 64)
        for (int idx = tid; idx < BK2*BN2; idx += 256) {
            int kk = idx / BN2, n = idx % BN2;
            int k = k0 + kk;
            #pragma unroll
            for (int q = 0; q < 4; ++q) {
                float v;
                if (k < WRANK)            v = Wm[q][(size_t)k*H_DIM + n0 + n];
                else if (k < WRANK+UR0)   v = Um[q][((size_t)g*UR0 + (k-WRANK))*HGD + jb + n];
                else                      v = UUm[q][((size_t)g*UR1 + (k-WRANK-UR0))*HGD + jb + n];
                Bs[q][kk][n] = v;
            }
        }
        __syncthreads();
        #pragma unroll
        for (int kk = 0; kk < BK2; ++kk) {
            float ra[TM2];
            #pragma unroll
            for (int i = 0; i < TM2; ++i) ra[i] = As[kk][trow*TM2 + i];
            #pragma unroll
            for (int q = 0; q < 4; ++q) {
                float rb[TN2];
                #pragma unroll
                for (int j = 0; j < TN2; ++j) rb[j] = Bs[q][kk][tcol*TN2 + j];
                #pragma unroll
                for (int i = 0; i < TM2; ++i)
                    #pragma unroll
                    for (int j = 0; j < TN2; ++j)
                        acc[q][i][j] += ra[i] * rb[j];
            }
        }
        __syncthreads();
    }

    // epilogue: gates -> c_next, h_next
    #pragma unroll
    for (int i = 0; i < TM2; ++i) {
        int b = m0 + trow*TM2 + i;
        #pragma unroll
        for (int j = 0; j < TN2; ++j) {
            int col = n0 + tcol*TN2 + j;
            float mi = acc[0][i][j] + bias_i[col];
            float mf = acc[1][i][j] + bias_f[col];
            float mo = acc[2][i][j] + bias_o[col];
            float mc = acc[3][i][j] + bias_c[col];
            float iv = 1.0f / (1.0f + expf(-mi));
            float fv = 1.0f / (1.0f + expf(-mf));
            float ov = 1.0f / (1.0f + expf(-mo));
            float ct = tanhf(mc);
            float cv = cin[(size_t)b*H_DIM + col];
            float cn = fv * cv + iv * ct;
            float hn = ov * tanhf(cn);
            c_out[(size_t)b*H_DIM + col] = cn;
            h_out[(size_t)b*H_DIM + col] = hn;
        }
    }
}

extern "C" void kernel_launch(void* const* d_in, const int* in_sizes, int n_in,
                              void* d_out, int out_size, void* d_ws, size_t ws_size,
                              hipStream_t stream)
{
    const float* x   = (const float*)d_in[0];
    const float* h   = (const float*)d_in[1];
    const float* c   = (const float*)d_in[2];
    const float* W   = (const float*)d_in[3];
    const float* W1  = (const float*)d_in[4];
    const float* W2  = (const float*)d_in[5];
    const float* W3  = (const float*)d_in[6];
    const float* W4  = (const float*)d_in[7];
    const float* U   = (const float*)d_in[8];
    const float* U1  = (const float*)d_in[9];
    const float* U2  = (const float*)d_in[10];
    const float* U3  = (const float*)d_in[11];
    const float* U4  = (const float*)d_in[12];
    const float* UU  = (const float*)d_in[13];
    const float* UU1 = (const float*)d_in[14];
    const float* UU2 = (const float*)d_in[15];
    const float* UU3 = (const float*)d_in[16];
    const float* UU4 = (const float*)d_in[17];
    const float* bias_f = (const float*)d_in[18];   // dict order: f, i, c, o
    const float* bias_i = (const float*)d_in[19];
    const float* bias_c = (const float*)d_in[20];
    const float* bias_o = (const float*)d_in[21];

    float* xw    = (float*)d_ws;                         // 8192*256 f32
    float* tUo   = xw  + (size_t)B_ROWS * WRANK;         // 8192*128 f32
    float* tUUo  = tUo + (size_t)B_ROWS * NG * UR0;      // 8192*64  f32
    float* c_out = (float*)d_out;
    float* h_out = c_out + (size_t)B_ROWS * H_DIM;

    dim3 blk(256);

    // Stage 1a: xw = x @ W   [8192x1024]@[1024x256]
    sgemm_kernel<64,64,32,4,4><<<dim3(WRANK/64, B_ROWS/64), blk, 0, stream>>>(
        x, IN_DIM, W, WRANK, xw, WRANK, B_ROWS, WRANK, IN_DIM);

    // Stage 1b/1c: grouped projections
    for (int g = 0; g < NG; ++g) {
        // tU[:,g,:] = h[:, g*512: (g+1)*512] @ U[g]   [8192x512]@[512x64]
        sgemm_kernel<64,64,32,4,4><<<dim3(1, B_ROWS/64), blk, 0, stream>>>(
            h + g*HGD, H_DIM, U + (size_t)g*HGD*UR0, UR0,
            tUo + g*UR0, NG*UR0, B_ROWS, UR0, HGD);
        // tUU[:,g,:] = h[:, ((g+1)%2)*512 : ...] @ UU[g]   (roll -1 on groups)
        sgemm_kernel<64,32,32,4,2><<<dim3(1, B_ROWS/64), blk, 0, stream>>>(
            h + ((g+1)%NG)*HGD, H_DIM, UU + (size_t)g*HGD*UR1, UR1,
            tUUo + g*UR1, NG*UR1, B_ROWS, UR1, HGD);
    }

    // Stage 2: fused 4-gate GEMM (K=352 concat) + LSTM pointwise epilogue
    lstm_gate_kernel<<<dim3(H_DIM/BN2, B_ROWS/BM2), blk, 0, stream>>>(
        xw, tUo, tUUo,
        W1, W2, W3, W4, U1, U2, U3, U4, UU1, UU2, UU3, UU4,
        bias_i, bias_f, bias_o, bias_c,
        c, c_out, h_out);
}

// Round 2
// 118.716 us; speedup vs baseline: 14.6921x; 14.6921x over previous
//
#include <hip/hip_runtime.h>
#include <hip/hip_bf16.h>

#define B_ROWS 8192
#define IN_DIM 1024
#define H_DIM  1024
#define WRANK  256
#define UR0    64
#define UR1    32
#define NG     2
#define HGD    512
#define KTOT   384      // concat K (256+64+32) zero-padded to 384
#define A2_LD  448      // xw(256) | tU0(64) | tUU0(32) | tU1(64) | tUU1(32)

typedef __attribute__((ext_vector_type(8))) short bf16x8;
typedef __attribute__((ext_vector_type(4))) float f32x4;
typedef __attribute__((ext_vector_type(4))) float float4v;

__device__ inline unsigned short f2bf(float f) {
    union { float f; unsigned u; } v; v.f = f;
    unsigned r = v.u + 0x7FFF + ((v.u >> 16) & 1);   // RNE
    return (unsigned short)(r >> 16);
}

// ---------------- weight pack: fp32 -> bf16, B operands transposed ----------------
__global__ __launch_bounds__(256)
void pack_weights(const float* __restrict__ W,
                  const float* __restrict__ W1, const float* __restrict__ W2,
                  const float* __restrict__ W3, const float* __restrict__ W4,
                  const float* __restrict__ U,  const float* __restrict__ U1,
                  const float* __restrict__ U2, const float* __restrict__ U3,
                  const float* __restrict__ U4,
                  const float* __restrict__ UU, const float* __restrict__ UU1,
                  const float* __restrict__ UU2,const float* __restrict__ UU3,
                  const float* __restrict__ UU4,
                  unsigned short* __restrict__ WbfT,
                  unsigned short* __restrict__ HPbfT,
                  unsigned short* __restrict__ GateBT)
{
    const float* Wg[4]  = {W1, W2, W3, W4};
    const float* Ug[4]  = {U1, U2, U3, U4};
    const float* UUg[4] = {UU1, UU2, UU3, UU4};
    const long N_WT = (long)WRANK * IN_DIM;    // 262144  WbfT[n][k] = W[k][n]
    const long N_HP = 192L * HGD;              // 98304
    const long N_GB = 4L * H_DIM * KTOT;       // 1572864
    const long total = N_WT + N_HP + N_GB;
    for (long t = blockIdx.x * 256L + threadIdx.x; t < total; t += (long)gridDim.x * 256L) {
        if (t < N_WT) {
            int n = (int)(t / IN_DIM), k = (int)(t % IN_DIM);
            WbfT[t] = f2bf(W[(size_t)k * WRANK + n]);
        } else if (t < N_WT + N_HP) {
            long u = t - N_WT;
            int r = (int)(u / HGD), k = (int)(u % HGD);
            float v;
            if (r < 64)       v = U [(size_t)k * UR0 + r];                 // U[0]^T
            else if (r < 96)  v = UU[(size_t)k * UR1 + (r - 64)];          // UU[0]^T
            else if (r < 160) v = U [(size_t)(HGD + k) * UR0 + (r - 96)];  // U[1]^T
            else              v = UU[(size_t)(HGD + k) * UR1 + (r - 160)]; // UU[1]^T
            HPbfT[u] = f2bf(v);
        } else {
            long u = t - N_WT - N_HP;
            int q  = (int)(u / ((long)H_DIM * KTOT));
            long w = u % ((long)H_DIM * KTOT);
            int n  = (int)(w / KTOT), kk = (int)(w % KTOT);
            int g = n >> 9, nn = n & 511;
            float v;
            if (kk < WRANK)                 v = Wg[q][(size_t)kk * H_DIM + n];
            else if (kk < WRANK + UR0)      v = Ug[q][((size_t)g * UR0 + (kk - WRANK)) * HGD + nn];
            else if (kk < WRANK + UR0 + UR1)v = UUg[q][((size_t)g * UR1 + (kk - WRANK - UR0)) * HGD + nn];
            else                            v = 0.f;
            GateBT[u] = f2bf(v);
        }
    }
}

// ---------------- templated MFMA GEMM ----------------
// MODE 0: A fp32 (x), C bf16 -> A2            (stage 1a)
// MODE 1: A fp32 (h) + per-n-tile col offset  (stage 1b)
// MODE 2: A bf16 (A2, concat-K), LSTM epilogue (stage 2, NQ=4 gates)
template<int BM, int BN, int BK, int WM, int WN, int MODE, int NQ>
__global__ __launch_bounds__(WM * WN * 64)
void gemm_mfma(const void* __restrict__ Aptr, int lda, int Kdim,
               const unsigned short* __restrict__ BT, int ldb,
               unsigned short* __restrict__ Cbf, int ldc, int c_col0,
               int offmask,
               const float* __restrict__ bias_f, const float* __restrict__ bias_i,
               const float* __restrict__ bias_c, const float* __restrict__ bias_o,
               const float* __restrict__ cin,
               float* __restrict__ cout, float* __restrict__ hout)
{
    constexpr int NT   = WM * WN * 64;
    constexpr int WTM  = BM / WM;
    constexpr int WTN  = BN / WN;
    constexpr int MI   = WTM / 16;
    constexpr int NJ   = WTN / 16;
    constexpr int ROWB = BK * 2;          // bytes per LDS row (BK=64 -> 128B, 8x16B chunks)
    static_assert(BK == 64, "staging assumes BK==64");

    __shared__ short As[BM * BK];
    __shared__ short Bs[NQ][BN * BK];

    const int tid  = threadIdx.x;
    const int wid  = tid >> 6, lane = tid & 63;
    const int wr   = wid / WN, wc = wid % WN;
    const int m0   = blockIdx.y * BM;
    const int n0   = blockIdx.x * BN;
    const int g    = (MODE == 2) ? (n0 >> 9) : 0;
    const int a_off = (MODE == 1) ? (((offmask >> blockIdx.x) & 1) * HGD) : 0;
    const int lane_r16 = lane & 15, lane_hi = lane >> 4;

    f32x4 acc[NQ][MI][NJ];
    #pragma unroll
    for (int q = 0; q < NQ; ++q)
        #pragma unroll
        for (int i = 0; i < MI; ++i)
            #pragma unroll
            for (int j = 0; j < NJ; ++j)
                acc[q][i][j] = (f32x4){0.f, 0.f, 0.f, 0.f};

    for (int k0 = 0; k0 < Kdim; k0 += BK) {
        __syncthreads();
        // ---- stage A tile [BM][BK] (16B chunks, XOR-swizzled) ----
        constexpr int ACH = BM * BK / 8;
        for (int c = tid; c < ACH; c += NT) {
            int row  = c >> 3;
            int slot = c & 7;
            int k    = k0 + slot * 8;
            int byte_off = row * ROWB + ((slot * 16) ^ ((row & 7) << 4));
            bf16x8 v;
            if (MODE == 2) {
                const unsigned short* A2 = (const unsigned short*)Aptr;
                if (k < WRANK) {
                    v = *(const bf16x8*)(A2 + (size_t)(m0 + row) * lda + k);
                } else if (k < WRANK + UR0 + UR1) {
                    v = *(const bf16x8*)(A2 + (size_t)(m0 + row) * lda + 96 * g + k);
                } else {
                    union { bf16x8 v; unsigned short s[8]; } z;
                    #pragma unroll
                    for (int e = 0; e < 8; ++e) z.s[e] = 0;
                    v = z.v;
                }
            } else {
                const float* Af = (const float*)Aptr;
                const float* p = Af + (size_t)(m0 + row) * lda + a_off + k;
                float4v f0 = *(const float4v*)p;
                float4v f1 = *(const float4v*)(p + 4);
                union { bf16x8 v; unsigned short s[8]; } u;
                u.s[0] = f2bf(f0.x); u.s[1] = f2bf(f0.y);
                u.s[2] = f2bf(f0.z); u.s[3] = f2bf(f0.w);
                u.s[4] = f2bf(f1.x); u.s[5] = f2bf(f1.y);
                u.s[6] = f2bf(f1.z); u.s[7] = f2bf(f1.w);
                v = u.v;
            }
            *(bf16x8*)((char*)As + byte_off) = v;
        }
        // ---- stage B^T tiles [BN][BK] per gate ----
        constexpr int BCH = BN * BK / 8;
        #pragma unroll
        for (int q = 0; q < NQ; ++q) {
            for (int c = tid; c < BCH; c += NT) {
                int row  = c >> 3;
                int slot = c & 7;
                int byte_off = row * ROWB + ((slot * 16) ^ ((row & 7) << 4));
                const unsigned short* src = BT
                    + (MODE == 2 ? (size_t)q * H_DIM * KTOT : (size_t)0)
                    + (size_t)(n0 + row) * ldb + k0 + slot * 8;
                *(bf16x8*)((char*)Bs[q] + byte_off) = *(const bf16x8*)src;
            }
        }
        __syncthreads();
        // ---- MFMA ----
        #pragma unroll
        for (int ks = 0; ks < BK / 32; ++ks) {
            bf16x8 af[MI];
            #pragma unroll
            for (int i = 0; i < MI; ++i) {
                int r = wr * WTM + i * 16 + lane_r16;
                int byte_off = r * ROWB + ((ks * 64 + lane_hi * 16) ^ ((r & 7) << 4));
                af[i] = *(const bf16x8*)((const char*)As + byte_off);
            }
            #pragma unroll
            for (int q = 0; q < NQ; ++q) {
                #pragma unroll
                for (int j = 0; j < NJ; ++j) {
                    int r = wc * WTN + j * 16 + lane_r16;
                    int byte_off = r * ROWB + ((ks * 64 + lane_hi * 16) ^ ((r & 7) << 4));
                    bf16x8 bfr = *(const bf16x8*)((const char*)Bs[q] + byte_off);
                    #pragma unroll
                    for (int i = 0; i < MI; ++i)
                        acc[q][i][j] = __builtin_amdgcn_mfma_f32_16x16x32_bf16(
                            af[i], bfr, acc[q][i][j], 0, 0, 0);
                }
            }
        }
    }

    if (MODE == 2) {
        #pragma unroll
        for (int i = 0; i < MI; ++i) {
            #pragma unroll
            for (int j = 0; j < NJ; ++j) {
                int ncol = n0 + wc * WTN + j * 16 + lane_r16;
                float Bi = bias_i[ncol], Bf = bias_f[ncol];
                float Bo = bias_o[ncol], Bc = bias_c[ncol];
                #pragma unroll
                for (int rr = 0; rr < 4; ++rr) {
                    int brow = m0 + wr * WTM + i * 16 + lane_hi * 4 + rr;
                    float mi = acc[0][i][j][rr] + Bi;
                    float mf = acc[1][i][j][rr] + Bf;
                    float mo = acc[2][i][j][rr] + Bo;
                    float mc = acc[3][i][j][rr] + Bc;
                    float iv = 1.f / (1.f + __expf(-mi));
                    float fv = 1.f / (1.f + __expf(-mf));
                    float ov = 1.f / (1.f + __expf(-mo));
                    float ct = tanhf(mc);
                    float cv = cin[(size_t)brow * H_DIM + ncol];
                    float cn = fv * cv + iv * ct;
                    float hn = ov * tanhf(cn);
                    cout[(size_t)brow * H_DIM + ncol] = cn;
                    hout[(size_t)brow * H_DIM + ncol] = hn;
                }
            }
        }
    } else {
        #pragma unroll
        for (int i = 0; i < MI; ++i) {
            #pragma unroll
            for (int j = 0; j < NJ; ++j) {
                int ncol = c_col0 + n0 + wc * WTN + j * 16 + lane_r16;
                #pragma unroll
                for (int rr = 0; rr < 4; ++rr) {
                    int brow = m0 + wr * WTM + i * 16 + lane_hi * 4 + rr;
                    Cbf[(size_t)brow * ldc + ncol] = f2bf(acc[0][i][j][rr]);
                }
            }
        }
    }
}

extern "C" void kernel_launch(void* const* d_in, const int* in_sizes, int n_in,
                              void* d_out, int out_size, void* d_ws, size_t ws_size,
                              hipStream_t stream)
{
    const float* x   = (const float*)d_in[0];
    const float* h   = (const float*)d_in[1];
    const float* c   = (const float*)d_in[2];
    const float* W   = (const float*)d_in[3];
    const float* W1  = (const float*)d_in[4];
    const float* W2  = (const float*)d_in[5];
    const float* W3  = (const float*)d_in[6];
    const float* W4  = (const float*)d_in[7];
    const float* U   = (const float*)d_in[8];
    const float* U1  = (const float*)d_in[9];
    const float* U2  = (const float*)d_in[10];
    const float* U3  = (const float*)d_in[11];
    const float* U4  = (const float*)d_in[12];
    const float* UU  = (const float*)d_in[13];
    const float* UU1 = (const float*)d_in[14];
    const float* UU2 = (const float*)d_in[15];
    const float* UU3 = (const float*)d_in[16];
    const float* UU4 = (const float*)d_in[17];
    const float* bias_f = (const float*)d_in[18];
    const float* bias_i = (const float*)d_in[19];
    const float* bias_c = (const float*)d_in[20];
    const float* bias_o = (const float*)d_in[21];

    unsigned short* A2     = (unsigned short*)d_ws;                        // [8192][448]
    unsigned short* WbfT   = A2   + (size_t)B_ROWS * A2_LD;                // [256][1024]
    unsigned short* HPbfT  = WbfT + (size_t)WRANK * IN_DIM;                // [192][512]
    unsigned short* GateBT = HPbfT + 192 * HGD;                            // [4][1024][384]

    float* c_out = (float*)d_out;
    float* h_out = c_out + (size_t)B_ROWS * H_DIM;

    // 1. pack weights to bf16 (transposed)
    pack_weights<<<dim3(2048), dim3(256), 0, stream>>>(
        W, W1, W2, W3, W4, U, U1, U2, U3, U4, UU, UU1, UU2, UU3, UU4,
        WbfT, HPbfT, GateBT);

    // 2. stage 1a: A2[:,0:256) = bf16( x @ W )
    gemm_mfma<128, 64, 64, 4, 2, 0, 1><<<dim3(WRANK / 64, B_ROWS / 128), dim3(512), 0, stream>>>(
        x, IN_DIM, IN_DIM, WbfT, IN_DIM, A2, A2_LD, 0, 0,
        nullptr, nullptr, nullptr, nullptr, nullptr, nullptr, nullptr);

    // 3. stage 1b: A2[:,256:448) = bf16( h-projections )  (per-tile h col offset mask)
    gemm_mfma<128, 32, 64, 4, 1, 1, 1><<<dim3(192 / 32, B_ROWS / 128), dim3(256), 0, stream>>>(
        h, H_DIM, HGD, HPbfT, HGD, A2, A2_LD, WRANK, 0x1C,
        nullptr, nullptr, nullptr, nullptr, nullptr, nullptr, nullptr);

    // 4. stage 2: fused 4-gate MFMA GEMM (K=384) + LSTM epilogue
    gemm_mfma<128, 64, 64, 4, 2, 2, 4><<<dim3(H_DIM / 64, B_ROWS / 128), dim3(512), 0, stream>>>(
        A2, A2_LD, KTOT, GateBT, KTOT, nullptr, 0, 0, 0,
        bias_f, bias_i, bias_c, bias_o, c, c_out, h_out);
}

// Round 3
// 97.299 us; speedup vs baseline: 17.9260x; 1.2201x over previous
//
#include <hip/hip_runtime.h>
#include <hip/hip_bf16.h>

#define B_ROWS 8192
#define IN_DIM 1024
#define H_DIM  1024
#define WRANK  256
#define UR0    64
#define UR1    32
#define HGD    512
#define KTOT   384      // stage-2 concat K: 256 + 64 + 32 + 32 pad
#define A2_LD  512      // xw(256) | tU0(64) tUU1(32) pad(32) | tU1(64) tUU0(32) pad(32)

typedef __attribute__((ext_vector_type(8))) short bf16x8;
typedef __attribute__((ext_vector_type(4))) float f32x4;
typedef __attribute__((ext_vector_type(4))) float float4v;

__device__ __forceinline__ unsigned short f2bf(float f) {
    union { float f; unsigned u; } v; v.f = f;
    unsigned r = v.u + 0x7FFF + ((v.u >> 16) & 1);   // RNE
    return (unsigned short)(r >> 16);
}

// async 16B global->LDS copy (dest = wave-uniform base + lane*16, done by HW)
__device__ __forceinline__ void gld16(void* lds, const void* g) {
    __builtin_amdgcn_global_load_lds(
        (const __attribute__((address_space(1))) unsigned int*)g,
        (__attribute__((address_space(3))) unsigned int*)lds, 16, 0, 0);
}

__device__ __forceinline__ float fsig(float x)  { return 1.f / (1.f + __expf(-x)); }
__device__ __forceinline__ float ftanh(float x) { return 1.f - 2.f / (__expf(2.f * x) + 1.f); }

// ---------------------------------------------------------------------------
// pack: fp32 weights -> bf16, transposed ([N][K]) and PRE-SWIZZLED:
// within each 128B span (64 cols), 16B chunk index is XOR'd with (n&7).
// WbfT [256][1024], HPbf [256][512], GateBT [4][1024][384].
// HPbf row semantics (h-group blocks): n<64:U0^T | n<96:UU1^T | n<128:0 |
//                                      n<192:U1^T | n<224:UU0^T | n<256:0
// ---------------------------------------------------------------------------
__global__ __launch_bounds__(256)
void pack_weights(const float* __restrict__ W,
                  const float* __restrict__ W1, const float* __restrict__ W2,
                  const float* __restrict__ W3, const float* __restrict__ W4,
                  const float* __restrict__ U,  const float* __restrict__ U1,
                  const float* __restrict__ U2, const float* __restrict__ U3,
                  const float* __restrict__ U4,
                  const float* __restrict__ UU, const float* __restrict__ UU1,
                  const float* __restrict__ UU2,const float* __restrict__ UU3,
                  const float* __restrict__ UU4,
                  unsigned short* __restrict__ WbfT,
                  unsigned short* __restrict__ HPbf,
                  unsigned short* __restrict__ GateBT)
{
    const float* Wg[4]  = {W1, W2, W3, W4};
    const float* Ug[4]  = {U1, U2, U3, U4};
    const float* UUg[4] = {UU1, UU2, UU3, UU4};
    const long N_WT = 256L * 1024;
    const long N_HP = 256L * 512;
    const long N_GB = 4L * 1024 * KTOT;
    const long total = N_WT + N_HP + N_GB;
    for (long t = blockIdx.x * 256L + threadIdx.x; t < total; t += (long)gridDim.x * 256L) {
        if (t < N_WT) {
            int n = (int)(t >> 10), p = (int)(t & 1023);
            int span = p >> 6, slp = (p >> 3) & 7, e = p & 7;
            int k = span * 64 + ((slp ^ (n & 7)) << 3) + e;
            WbfT[t] = f2bf(W[(size_t)k * WRANK + n]);
        } else if (t < N_WT + N_HP) {
            long u = t - N_WT;
            int n = (int)(u >> 9), p = (int)(u & 511);
            int span = p >> 6, slp = (p >> 3) & 7, e = p & 7;
            int k = span * 64 + ((slp ^ (n & 7)) << 3) + e;
            float v;
            if (n < 64)       v = U [(size_t)k * UR0 + n];
            else if (n < 96)  v = UU[(size_t)(HGD + k) * UR1 + (n - 64)];
            else if (n < 128) v = 0.f;
            else if (n < 192) v = U [(size_t)(HGD + k) * UR0 + (n - 128)];
            else if (n < 224) v = UU[(size_t)k * UR1 + (n - 192)];
            else              v = 0.f;
            HPbf[u] = f2bf(v);
        } else {
            long u = t - N_WT - N_HP;
            int q = (int)(u / (1024L * KTOT));
            long w = u - (long)q * 1024 * KTOT;
            int n = (int)(w / KTOT), p = (int)(w % KTOT);
            int span = p >> 6, slp = (p >> 3) & 7, e = p & 7;
            int k = span * 64 + ((slp ^ (n & 7)) << 3) + e;
            int g = n >> 9, nn = n & 511;
            float v;
            if (k < WRANK)            v = Wg[q][(size_t)k * H_DIM + n];
            else if (k < WRANK + UR0) v = Ug[q][((size_t)g * UR0 + (k - WRANK)) * HGD + nn];
            else if (k < 352)         v = UUg[q][((size_t)g * UR1 + (k - 320)) * HGD + nn];
            else                      v = 0.f;
            GateBT[u] = f2bf(v);
        }
    }
}

// ---------------------------------------------------------------------------
// stage 1 (fused 1a+1b): A2[:,0:256) = bf16(x@W), A2[:,256:512) = bf16(h-projs)
// BM=128 BN=64 BK=64, 4 waves (WTM=64 WTN=32, MI=4 NJ=2). A reg-staged
// (fp32->bf16), B via global_load_lds from pre-swizzled weights.
// ---------------------------------------------------------------------------
__global__ __launch_bounds__(256, 2)
void s1_kernel(const float* __restrict__ x, const float* __restrict__ h,
               const unsigned short* __restrict__ WbfT,
               const unsigned short* __restrict__ HPbf,
               unsigned short* __restrict__ A2)
{
    __shared__ short As[128 * 64];
    __shared__ short Bs[64 * 64];

    const int flat = blockIdx.x;                 // 512 blocks
    const int id = (flat & 7) * 64 + (flat >> 3);
    const int bx = id & 7, by = id >> 3;
    const int m0 = by * 128;

    const bool pa = bx < 4;
    const int Kdim = pa ? IN_DIM : HGD;
    const float* Af = pa ? x : h;
    const int a_off = pa ? 0 : ((bx - 4) >> 1) * HGD;
    const unsigned short* Bw = pa ? (WbfT + (size_t)(bx * 64) * IN_DIM)
                                  : (HPbf + (size_t)((bx - 4) * 64) * HGD);
    const int ldbw = pa ? IN_DIM : HGD;
    const int ccol0 = pa ? bx * 64 : WRANK + (bx - 4) * 64;

    const int tid = threadIdx.x, lane = tid & 63, wid = tid >> 6;
    const int wr = wid >> 1, wc = wid & 1;
    const int lr = lane & 15, lh = lane >> 4;

    f32x4 acc[4][2];
    #pragma unroll
    for (int i = 0; i < 4; ++i)
        #pragma unroll
        for (int j = 0; j < 2; ++j) acc[i][j] = (f32x4){0.f, 0.f, 0.f, 0.f};

    for (int k0 = 0; k0 < Kdim; k0 += 64) {
        // B: 8 row-units of 8 rows x 128B, 2 per wave, async direct to LDS
        #pragma unroll
        for (int t = 0; t < 2; ++t) {
            int u = wid + t * 4;
            const char* src = (const char*)Bw
                + ((size_t)(u * 8 + (lane >> 3)) * ldbw + k0) * 2 + (lane & 7) * 16;
            gld16((char*)Bs + u * 1024, src);
        }
        // A: fp32 -> bf16, swizzled ds_write
        #pragma unroll
        for (int t = 0; t < 4; ++t) {
            int c = tid + t * 256;
            int row = c >> 3, slot = c & 7;
            const float* p = Af + (size_t)(m0 + row) * 1024 + a_off + k0 + slot * 8;
            float4v f0 = *(const float4v*)p, f1 = *(const float4v*)(p + 4);
            union { bf16x8 v; unsigned short s[8]; } uv;
            uv.s[0] = f2bf(f0.x); uv.s[1] = f2bf(f0.y);
            uv.s[2] = f2bf(f0.z); uv.s[3] = f2bf(f0.w);
            uv.s[4] = f2bf(f1.x); uv.s[5] = f2bf(f1.y);
            uv.s[6] = f2bf(f1.z); uv.s[7] = f2bf(f1.w);
            *(bf16x8*)((char*)As + row * 128 + ((slot ^ (row & 7)) << 4)) = uv.v;
        }
        __syncthreads();
        #pragma unroll
        for (int ks = 0; ks < 2; ++ks) {
            bf16x8 af[4];
            #pragma unroll
            for (int i = 0; i < 4; ++i) {
                int r = wr * 64 + i * 16 + lr;
                af[i] = *(const bf16x8*)((const char*)As + r * 128 + (((ks * 4 + lh) ^ (r & 7)) << 4));
            }
            #pragma unroll
            for (int j = 0; j < 2; ++j) {
                int r = wc * 32 + j * 16 + lr;
                bf16x8 rb = *(const bf16x8*)((const char*)Bs + r * 128 + (((ks * 4 + lh) ^ (r & 7)) << 4));
                #pragma unroll
                for (int i = 0; i < 4; ++i)
                    acc[i][j] = __builtin_amdgcn_mfma_f32_16x16x32_bf16(af[i], rb, acc[i][j], 0, 0, 0);
            }
        }
        __syncthreads();
    }

    // epilogue: write A2 bf16, PRE-SWIZZLED layout
    #pragma unroll
    for (int i = 0; i < 4; ++i) {
        #pragma unroll
        for (int j = 0; j < 2; ++j) {
            int ncol = ccol0 + wc * 32 + j * 16 + lr;
            int span = ncol >> 6, sl = (ncol >> 3) & 7, e = ncol & 7;
            #pragma unroll
            for (int rr = 0; rr < 4; ++rr) {
                int brow = m0 + wr * 64 + i * 16 + lh * 4 + rr;
                int phys = span * 64 + ((sl ^ (brow & 7)) << 3) + e;
                A2[(size_t)brow * A2_LD + phys] = f2bf(acc[i][j][rr]);
            }
        }
    }
}

// ---------------------------------------------------------------------------
// stage 2: 4-gate MFMA GEMM (K=384 concat) + LSTM epilogue.
// BM=128 BN=64 NQ=4, 4 waves (WTM=64 WTN=32, MI=4 NJ=2), BK=64, all staging
// via global_load_lds from pre-swizzled A2 / GateBT.
// ---------------------------------------------------------------------------
__global__ __launch_bounds__(256, 2)
void s2_kernel(const unsigned short* __restrict__ A2,
               const unsigned short* __restrict__ GateBT,
               const float* __restrict__ bias_f, const float* __restrict__ bias_i,
               const float* __restrict__ bias_c, const float* __restrict__ bias_o,
               const float* __restrict__ cin,
               float* __restrict__ cout, float* __restrict__ hout)
{
    __shared__ short As[128 * 64];
    __shared__ short Bs[4][64 * 64];

    const int flat = blockIdx.x;                  // 1024 blocks
    const int id = (flat & 7) * 128 + (flat >> 3);
    const int nt = id & 15, mt = id >> 4;
    const int m0 = mt * 128, n0 = nt * 64, g = n0 >> 9;

    const int tid = threadIdx.x, lane = tid & 63, wid = tid >> 6;
    const int wr = wid >> 1, wc = wid & 1;
    const int lr = lane & 15, lh = lane >> 4;

    f32x4 acc[4][4][2];
    #pragma unroll
    for (int q = 0; q < 4; ++q)
        #pragma unroll
        for (int i = 0; i < 4; ++i)
            #pragma unroll
            for (int j = 0; j < 2; ++j) acc[q][i][j] = (f32x4){0.f, 0.f, 0.f, 0.f};

    for (int s = 0; s < 6; ++s) {
        // memory span for A (concat-K + group offset): s<4 -> s ; tU_g ; tUU_g|pad
        const int ms = (s < 4) ? s : ((s == 4) ? 4 + 2 * g : 5 + 2 * (g ^ 1));
        // A: 16 units of 8 rows x 128B
        #pragma unroll
        for (int t = 0; t < 4; ++t) {
            int u = wid * 4 + t;
            const char* src = (const char*)A2
                + (size_t)(m0 + u * 8 + (lane >> 3)) * (A2_LD * 2) + ms * 128 + (lane & 7) * 16;
            gld16((char*)As + u * 1024, src);
        }
        // B: 4 gates x 8 units
        #pragma unroll
        for (int t = 0; t < 8; ++t) {
            int q = t >> 1;
            int u = (t & 1) * 4 + wid;
            const char* src = (const char*)GateBT
                + (size_t)(q * 1024 + n0 + u * 8 + (lane >> 3)) * (KTOT * 2) + s * 128 + (lane & 7) * 16;
            gld16((char*)Bs[q] + u * 1024, src);
        }
        __syncthreads();
        #pragma unroll
        for (int ks = 0; ks < 2; ++ks) {
            bf16x8 af[4];
            #pragma unroll
            for (int i = 0; i < 4; ++i) {
                int r = wr * 64 + i * 16 + lr;
                af[i] = *(const bf16x8*)((const char*)As + r * 128 + (((ks * 4 + lh) ^ (r & 7)) << 4));
            }
            #pragma unroll
            for (int q = 0; q < 4; ++q) {
                #pragma unroll
                for (int j = 0; j < 2; ++j) {
                    int r = wc * 32 + j * 16 + lr;
                    bf16x8 rb = *(const bf16x8*)((const char*)Bs[q] + r * 128 + (((ks * 4 + lh) ^ (r & 7)) << 4));
                    #pragma unroll
                    for (int i = 0; i < 4; ++i)
                        acc[q][i][j] = __builtin_amdgcn_mfma_f32_16x16x32_bf16(af[i], rb, acc[q][i][j], 0, 0, 0);
                }
            }
        }
        __syncthreads();
    }

    // epilogue: gates -> c_next, h_next
    #pragma unroll
    for (int j = 0; j < 2; ++j) {
        int ncol = n0 + wc * 32 + j * 16 + lr;
        float Bi = bias_i[ncol], Bf = bias_f[ncol];
        float Bo = bias_o[ncol], Bc = bias_c[ncol];
        #pragma unroll
        for (int i = 0; i < 4; ++i) {
            #pragma unroll
            for (int rr = 0; rr < 4; ++rr) {
                int brow = m0 + wr * 64 + i * 16 + lh * 4 + rr;
                float mi = acc[0][i][j][rr] + Bi;
                float mf = acc[1][i][j][rr] + Bf;
                float mo = acc[2][i][j][rr] + Bo;
                float mc = acc[3][i][j][rr] + Bc;
                float iv = fsig(mi), fv = fsig(mf), ov = fsig(mo);
                float ct = ftanh(mc);
                float cv = cin[(size_t)brow * H_DIM + ncol];
                float cn = fv * cv + iv * ct;
                float hn = ov * ftanh(cn);
                cout[(size_t)brow * H_DIM + ncol] = cn;
                hout[(size_t)brow * H_DIM + ncol] = hn;
            }
        }
    }
}

extern "C" void kernel_launch(void* const* d_in, const int* in_sizes, int n_in,
                              void* d_out, int out_size, void* d_ws, size_t ws_size,
                              hipStream_t stream)
{
    const float* x   = (const float*)d_in[0];
    const float* h   = (const float*)d_in[1];
    const float* c   = (const float*)d_in[2];
    const float* W   = (const float*)d_in[3];
    const float* W1  = (const float*)d_in[4];
    const float* W2  = (const float*)d_in[5];
    const float* W3  = (const float*)d_in[6];
    const float* W4  = (const float*)d_in[7];
    const float* U   = (const float*)d_in[8];
    const float* U1  = (const float*)d_in[9];
    const float* U2  = (const float*)d_in[10];
    const float* U3  = (const float*)d_in[11];
    const float* U4  = (const float*)d_in[12];
    const float* UU  = (const float*)d_in[13];
    const float* UU1 = (const float*)d_in[14];
    const float* UU2 = (const float*)d_in[15];
    const float* UU3 = (const float*)d_in[16];
    const float* UU4 = (const float*)d_in[17];
    const float* bias_f = (const float*)d_in[18];
    const float* bias_i = (const float*)d_in[19];
    const float* bias_c = (const float*)d_in[20];
    const float* bias_o = (const float*)d_in[21];

    unsigned short* A2     = (unsigned short*)d_ws;                 // [8192][512]
    unsigned short* WbfT   = A2   + (size_t)B_ROWS * A2_LD;         // [256][1024]
    unsigned short* HPbf   = WbfT + 256L * 1024;                    // [256][512]
    unsigned short* GateBT = HPbf + 256L * 512;                     // [4][1024][384]

    float* c_out = (float*)d_out;
    float* h_out = c_out + (size_t)B_ROWS * H_DIM;

    pack_weights<<<dim3(2048), dim3(256), 0, stream>>>(
        W, W1, W2, W3, W4, U, U1, U2, U3, U4, UU, UU1, UU2, UU3, UU4,
        WbfT, HPbf, GateBT);

    s1_kernel<<<dim3(512), dim3(256), 0, stream>>>(x, h, WbfT, HPbf, A2);

    s2_kernel<<<dim3(1024), dim3(256), 0, stream>>>(
        A2, GateBT, bias_f, bias_i, bias_c, bias_o, c, c_out, h_out);
}

// Round 4
// 93.997 us; speedup vs baseline: 18.5557x; 1.0351x over previous
//
#include <hip/hip_runtime.h>
#include <hip/hip_bf16.h>

#define B_ROWS 8192
#define IN_DIM 1024
#define H_DIM  1024
#define WRANK  256
#define UR0    64
#define UR1    32
#define HGD    512
#define KTOT   384      // stage-2 concat K: 256 + 64 + 32 + 32 pad
#define A2_LD  512      // xw(256) | tU0(64) tUU1(32) pad(32) | tU1(64) tUU0(32) pad(32)

typedef __attribute__((ext_vector_type(8))) short bf16x8;
typedef __attribute__((ext_vector_type(4))) float f32x4;
typedef __attribute__((ext_vector_type(4))) float float4v;

__device__ __forceinline__ unsigned short f2bf(float f) {
    union { float f; unsigned u; } v; v.f = f;
    unsigned r = v.u + 0x7FFF + ((v.u >> 16) & 1);   // RNE
    return (unsigned short)(r >> 16);
}

// async 16B global->LDS copy (dest = wave-uniform base + lane*16, done by HW)
__device__ __forceinline__ void gld16(void* lds, const void* g) {
    __builtin_amdgcn_global_load_lds(
        (const __attribute__((address_space(1))) unsigned int*)g,
        (__attribute__((address_space(3))) unsigned int*)lds, 16, 0, 0);
}

__device__ __forceinline__ float fsig(float x)  { return 1.f / (1.f + __expf(-x)); }
__device__ __forceinline__ float ftanh(float x) { return 1.f - 2.f / (__expf(2.f * x) + 1.f); }

// ---------------------------------------------------------------------------
// pack: fp32 weights -> bf16, transposed ([N][K]) and PRE-SWIZZLED:
// within each 128B span (64 cols), 16B chunk index is XOR'd with (n&7).
// WbfT [256][1024], HPbf [256][512], GateBT [4][1024][384].
// HPbf row semantics (h-group blocks): n<64:U0^T | n<96:UU1^T | n<128:0 |
//                                      n<192:U1^T | n<224:UU0^T | n<256:0
// ---------------------------------------------------------------------------
__global__ __launch_bounds__(256)
void pack_weights(const float* __restrict__ W,
                  const float* __restrict__ W1, const float* __restrict__ W2,
                  const float* __restrict__ W3, const float* __restrict__ W4,
                  const float* __restrict__ U,  const float* __restrict__ U1,
                  const float* __restrict__ U2, const float* __restrict__ U3,
                  const float* __restrict__ U4,
                  const float* __restrict__ UU, const float* __restrict__ UU1,
                  const float* __restrict__ UU2,const float* __restrict__ UU3,
                  const float* __restrict__ UU4,
                  unsigned short* __restrict__ WbfT,
                  unsigned short* __restrict__ HPbf,
                  unsigned short* __restrict__ GateBT)
{
    const float* Wg[4]  = {W1, W2, W3, W4};
    const float* Ug[4]  = {U1, U2, U3, U4};
    const float* UUg[4] = {UU1, UU2, UU3, UU4};
    const long N_WT = 256L * 1024;
    const long N_HP = 256L * 512;
    const long N_GB = 4L * 1024 * KTOT;
    const long total = N_WT + N_HP + N_GB;
    for (long t = blockIdx.x * 256L + threadIdx.x; t < total; t += (long)gridDim.x * 256L) {
        if (t < N_WT) {
            int n = (int)(t >> 10), p = (int)(t & 1023);
            int span = p >> 6, slp = (p >> 3) & 7, e = p & 7;
            int k = span * 64 + ((slp ^ (n & 7)) << 3) + e;
            WbfT[t] = f2bf(W[(size_t)k * WRANK + n]);
        } else if (t < N_WT + N_HP) {
            long u = t - N_WT;
            int n = (int)(u >> 9), p = (int)(u & 511);
            int span = p >> 6, slp = (p >> 3) & 7, e = p & 7;
            int k = span * 64 + ((slp ^ (n & 7)) << 3) + e;
            float v;
            if (n < 64)       v = U [(size_t)k * UR0 + n];
            else if (n < 96)  v = UU[(size_t)(HGD + k) * UR1 + (n - 64)];
            else if (n < 128) v = 0.f;
            else if (n < 192) v = U [(size_t)(HGD + k) * UR0 + (n - 128)];
            else if (n < 224) v = UU[(size_t)k * UR1 + (n - 192)];
            else              v = 0.f;
            HPbf[u] = f2bf(v);
        } else {
            long u = t - N_WT - N_HP;
            int q = (int)(u / (1024L * KTOT));
            long w = u - (long)q * 1024 * KTOT;
            int n = (int)(w / KTOT), p = (int)(w % KTOT);
            int span = p >> 6, slp = (p >> 3) & 7, e = p & 7;
            int k = span * 64 + ((slp ^ (n & 7)) << 3) + e;
            int g = n >> 9, nn = n & 511;
            float v;
            if (k < WRANK)            v = Wg[q][(size_t)k * H_DIM + n];
            else if (k < WRANK + UR0) v = Ug[q][((size_t)g * UR0 + (k - WRANK)) * HGD + nn];
            else if (k < 352)         v = UUg[q][((size_t)g * UR1 + (k - 320)) * HGD + nn];
            else                      v = 0.f;
            GateBT[u] = f2bf(v);
        }
    }
}

// ---------------------------------------------------------------------------
// stage 1 (fused 1a+1b): A2[:,0:256) = bf16(x@W), A2[:,256:512) = bf16(h-projs)
// BM=128 BN=64 BK=64, 4 waves (WTM=64 WTN=32, MI=4 NJ=2). A reg-staged
// (fp32->bf16), B via global_load_lds from pre-swizzled weights.
// ---------------------------------------------------------------------------
__global__ __launch_bounds__(256, 2)
void s1_kernel(const float* __restrict__ x, const float* __restrict__ h,
               const unsigned short* __restrict__ WbfT,
               const unsigned short* __restrict__ HPbf,
               unsigned short* __restrict__ A2)
{
    __shared__ short As[128 * 64];
    __shared__ short Bs[64 * 64];

    const int flat = blockIdx.x;                 // 512 blocks
    const int id = (flat & 7) * 64 + (flat >> 3);
    const int bx = id & 7, by = id >> 3;
    const int m0 = by * 128;

    const bool pa = bx < 4;
    const int Kdim = pa ? IN_DIM : HGD;
    const float* Af = pa ? x : h;
    const int a_off = pa ? 0 : ((bx - 4) >> 1) * HGD;
    const unsigned short* Bw = pa ? (WbfT + (size_t)(bx * 64) * IN_DIM)
                                  : (HPbf + (size_t)((bx - 4) * 64) * HGD);
    const int ldbw = pa ? IN_DIM : HGD;
    const int ccol0 = pa ? bx * 64 : WRANK + (bx - 4) * 64;

    const int tid = threadIdx.x, lane = tid & 63, wid = tid >> 6;
    const int wr = wid >> 1, wc = wid & 1;
    const int lr = lane & 15, lh = lane >> 4;

    f32x4 acc[4][2];
    #pragma unroll
    for (int i = 0; i < 4; ++i)
        #pragma unroll
        for (int j = 0; j < 2; ++j) acc[i][j] = (f32x4){0.f, 0.f, 0.f, 0.f};

    for (int k0 = 0; k0 < Kdim; k0 += 64) {
        // B: 8 row-units of 8 rows x 128B, 2 per wave, async direct to LDS
        #pragma unroll
        for (int t = 0; t < 2; ++t) {
            int u = wid + t * 4;
            const char* src = (const char*)Bw
                + ((size_t)(u * 8 + (lane >> 3)) * ldbw + k0) * 2 + (lane & 7) * 16;
            gld16((char*)Bs + u * 1024, src);
        }
        // A: fp32 -> bf16, swizzled ds_write
        #pragma unroll
        for (int t = 0; t < 4; ++t) {
            int c = tid + t * 256;
            int row = c >> 3, slot = c & 7;
            const float* p = Af + (size_t)(m0 + row) * 1024 + a_off + k0 + slot * 8;
            float4v f0 = *(const float4v*)p, f1 = *(const float4v*)(p + 4);
            union { bf16x8 v; unsigned short s[8]; } uv;
            uv.s[0] = f2bf(f0.x); uv.s[1] = f2bf(f0.y);
            uv.s[2] = f2bf(f0.z); uv.s[3] = f2bf(f0.w);
            uv.s[4] = f2bf(f1.x); uv.s[5] = f2bf(f1.y);
            uv.s[6] = f2bf(f1.z); uv.s[7] = f2bf(f1.w);
            *(bf16x8*)((char*)As + row * 128 + ((slot ^ (row & 7)) << 4)) = uv.v;
        }
        __syncthreads();
        #pragma unroll
        for (int ks = 0; ks < 2; ++ks) {
            bf16x8 af[4];
            #pragma unroll
            for (int i = 0; i < 4; ++i) {
                int r = wr * 64 + i * 16 + lr;
                af[i] = *(const bf16x8*)((const char*)As + r * 128 + (((ks * 4 + lh) ^ (r & 7)) << 4));
            }
            #pragma unroll
            for (int j = 0; j < 2; ++j) {
                int r = wc * 32 + j * 16 + lr;
                bf16x8 rb = *(const bf16x8*)((const char*)Bs + r * 128 + (((ks * 4 + lh) ^ (r & 7)) << 4));
                #pragma unroll
                for (int i = 0; i < 4; ++i)
                    acc[i][j] = __builtin_amdgcn_mfma_f32_16x16x32_bf16(af[i], rb, acc[i][j], 0, 0, 0);
            }
        }
        __syncthreads();
    }

    // epilogue: write A2 bf16, PRE-SWIZZLED layout
    #pragma unroll
    for (int i = 0; i < 4; ++i) {
        #pragma unroll
        for (int j = 0; j < 2; ++j) {
            int ncol = ccol0 + wc * 32 + j * 16 + lr;
            int span = ncol >> 6, sl = (ncol >> 3) & 7, e = ncol & 7;
            #pragma unroll
            for (int rr = 0; rr < 4; ++rr) {
                int brow = m0 + wr * 64 + i * 16 + lh * 4 + rr;
                int phys = span * 64 + ((sl ^ (brow & 7)) << 3) + e;
                A2[(size_t)brow * A2_LD + phys] = f2bf(acc[i][j][rr]);
            }
        }
    }
}

// ---------------------------------------------------------------------------
// stage 2: 4-gate MFMA GEMM (K=384 concat) + LSTM epilogue.
// BM=256 BN=64 NQ=4, 8 waves (wave tile 64x32x4g, MI=4 NJ=2), BK=64.
// Double-buffered LDS (128 KB), prefetch depth 1 with counted vmcnt(8),
// raw s_barrier (no vmcnt(0) drain in steady state), setprio around MFMA.
// All operands pre-swizzled in memory -> linear global_load_lds.
// ---------------------------------------------------------------------------
__global__ __launch_bounds__(512, 2)
void s2_kernel(const unsigned short* __restrict__ A2,
               const unsigned short* __restrict__ GateBT,
               const float* __restrict__ bias_f, const float* __restrict__ bias_i,
               const float* __restrict__ bias_c, const float* __restrict__ bias_o,
               const float* __restrict__ cin,
               float* __restrict__ cout, float* __restrict__ hout)
{
    __shared__ short As[2][256 * 64];        // 2 x 32 KB
    __shared__ short Bs[2][4][64 * 64];      // 2 x 32 KB

    const int flat = blockIdx.x;             // 512 blocks, 512 % 8 == 0 -> bijective
    const int id = (flat & 7) * 64 + (flat >> 3);
    const int nt = id & 15, mt = id >> 4;
    const int m0 = mt * 256, n0 = nt * 64, g = n0 >> 9;

    const int tid = threadIdx.x, lane = tid & 63, wid = tid >> 6;
    const int wr = wid >> 1, wc = wid & 1;   // 4 x 2 wave grid
    const int lr = lane & 15, lh = lane >> 4;
    const int l8 = lane >> 3, l7 = lane & 7;

    f32x4 acc[4][4][2];
    #pragma unroll
    for (int q = 0; q < 4; ++q)
        #pragma unroll
        for (int i = 0; i < 4; ++i)
            #pragma unroll
            for (int j = 0; j < 2; ++j) acc[q][i][j] = (f32x4){0.f, 0.f, 0.f, 0.f};

    // stage k-span s into buffer buf: 8 gld16 per wave (4 A units + 4 B units)
#define STAGE_S2(buf, s) do {                                                        \
    const int _ms = ((s) < 4) ? (s) : (((s) == 4) ? 4 + 2 * g : 5 + 2 * (g ^ 1));    \
    _Pragma("unroll")                                                                \
    for (int t = 0; t < 4; ++t) {                                                    \
        int u = wid * 4 + t;                                                         \
        gld16((char*)&As[buf][0] + u * 1024,                                         \
              (const char*)A2 + ((size_t)(m0 + u * 8 + l8) * A2_LD + _ms * 64) * 2   \
              + l7 * 16);                                                            \
    }                                                                                \
    _Pragma("unroll")                                                                \
    for (int t = 0; t < 4; ++t) {                                                    \
        int v = wid * 4 + t, q = v >> 3, uu = v & 7;                                 \
        gld16((char*)&Bs[buf][q][0] + uu * 1024,                                     \
              (const char*)GateBT + ((size_t)(q * 1024 + n0 + uu * 8 + l8) * KTOT    \
              + (s) * 64) * 2 + l7 * 16);                                            \
    } } while (0)

    STAGE_S2(0, 0);

    #pragma unroll
    for (int s = 0; s < 6; ++s) {
        const int cur = s & 1;
        if (s < 5) {
            STAGE_S2(cur ^ 1, s + 1);
            asm volatile("s_waitcnt vmcnt(8)" ::: "memory");  // drain tile s only
        } else {
            asm volatile("s_waitcnt vmcnt(0)" ::: "memory");
        }
        __builtin_amdgcn_s_barrier();
        asm volatile("" ::: "memory");
        __builtin_amdgcn_s_setprio(1);
        #pragma unroll
        for (int ks = 0; ks < 2; ++ks) {
            bf16x8 af[4];
            #pragma unroll
            for (int i = 0; i < 4; ++i) {
                int r = wr * 64 + i * 16 + lr;
                af[i] = *(const bf16x8*)((const char*)&As[cur][0] + r * 128
                        + (((ks * 4 + lh) ^ (r & 7)) << 4));
            }
            #pragma unroll
            for (int q = 0; q < 4; ++q) {
                #pragma unroll
                for (int j = 0; j < 2; ++j) {
                    int r = wc * 32 + j * 16 + lr;
                    bf16x8 rb = *(const bf16x8*)((const char*)&Bs[cur][q][0] + r * 128
                                + (((ks * 4 + lh) ^ (r & 7)) << 4));
                    #pragma unroll
                    for (int i = 0; i < 4; ++i)
                        acc[q][i][j] = __builtin_amdgcn_mfma_f32_16x16x32_bf16(
                            af[i], rb, acc[q][i][j], 0, 0, 0);
                }
            }
        }
        __builtin_amdgcn_s_setprio(0);
        asm volatile("" ::: "memory");   // ds_reads stay above the barrier
        __builtin_amdgcn_s_barrier();    // buffer safe to overwrite next iter
        asm volatile("" ::: "memory");
    }
#undef STAGE_S2

    // epilogue: gates -> c_next, h_next
    #pragma unroll
    for (int j = 0; j < 2; ++j) {
        int ncol = n0 + wc * 32 + j * 16 + lr;
        float Bi = bias_i[ncol], Bf = bias_f[ncol];
        float Bo = bias_o[ncol], Bc = bias_c[ncol];
        #pragma unroll
        for (int i = 0; i < 4; ++i) {
            #pragma unroll
            for (int rr = 0; rr < 4; ++rr) {
                int brow = m0 + wr * 64 + i * 16 + lh * 4 + rr;
                float mi = acc[0][i][j][rr] + Bi;
                float mf = acc[1][i][j][rr] + Bf;
                float mo = acc[2][i][j][rr] + Bo;
                float mc = acc[3][i][j][rr] + Bc;
                float iv = fsig(mi), fv = fsig(mf), ov = fsig(mo);
                float ct = ftanh(mc);
                float cv = cin[(size_t)brow * H_DIM + ncol];
                float cn = fv * cv + iv * ct;
                float hn = ov * ftanh(cn);
                cout[(size_t)brow * H_DIM + ncol] = cn;
                hout[(size_t)brow * H_DIM + ncol] = hn;
            }
        }
    }
}

extern "C" void kernel_launch(void* const* d_in, const int* in_sizes, int n_in,
                              void* d_out, int out_size, void* d_ws, size_t ws_size,
                              hipStream_t stream)
{
    const float* x   = (const float*)d_in[0];
    const float* h   = (const float*)d_in[1];
    const float* c   = (const float*)d_in[2];
    const float* W   = (const float*)d_in[3];
    const float* W1  = (const float*)d_in[4];
    const float* W2  = (const float*)d_in[5];
    const float* W3  = (const float*)d_in[6];
    const float* W4  = (const float*)d_in[7];
    const float* U   = (const float*)d_in[8];
    const float* U1  = (const float*)d_in[9];
    const float* U2  = (const float*)d_in[10];
    const float* U3  = (const float*)d_in[11];
    const float* U4  = (const float*)d_in[12];
    const float* UU  = (const float*)d_in[13];
    const float* UU1 = (const float*)d_in[14];
    const float* UU2 = (const float*)d_in[15];
    const float* UU3 = (const float*)d_in[16];
    const float* UU4 = (const float*)d_in[17];
    const float* bias_f = (const float*)d_in[18];
    const float* bias_i = (const float*)d_in[19];
    const float* bias_c = (const float*)d_in[20];
    const float* bias_o = (const float*)d_in[21];

    unsigned short* A2     = (unsigned short*)d_ws;                 // [8192][512]
    unsigned short* WbfT   = A2   + (size_t)B_ROWS * A2_LD;         // [256][1024]
    unsigned short* HPbf   = WbfT + 256L * 1024;                    // [256][512]
    unsigned short* GateBT = HPbf + 256L * 512;                     // [4][1024][384]

    float* c_out = (float*)d_out;
    float* h_out = c_out + (size_t)B_ROWS * H_DIM;

    pack_weights<<<dim3(2048), dim3(256), 0, stream>>>(
        W, W1, W2, W3, W4, U, U1, U2, U3, U4, UU, UU1, UU2, UU3, UU4,
        WbfT, HPbf, GateBT);

    s1_kernel<<<dim3(512), dim3(256), 0, stream>>>(x, h, WbfT, HPbf, A2);

    s2_kernel<<<dim3(512), dim3(512), 0, stream>>>(
        A2, GateBT, bias_f, bias_i, bias_c, bias_o, c, c_out, h_out);
}

// Round 5
// 84.220 us; speedup vs baseline: 20.7097x; 1.1161x over previous
//
#include <hip/hip_runtime.h>
#include <hip/hip_bf16.h>

#define B_ROWS 8192
#define IN_DIM 1024
#define H_DIM  1024
#define WRANK  256
#define UR0    64
#define UR1    32
#define HGD    512

// stage-2 concat K = 256 + 64 + 32 = 352 -> 11 k-tiles of 32
#define NS2    11
// A2T: per 256-row panel, 14 physical k-tiles: 0..7 xw | 8,9 tU0 | 10 tUU1 | 11,12 tU1 | 13 tUU0
#define NTA    14
// tile image: [kc 0..3][rows][8 elems] ; 256-row tile = 8192 elems = 16KB

typedef __attribute__((ext_vector_type(8))) short bf16x8;
typedef __attribute__((ext_vector_type(4))) float f32x4;
typedef __attribute__((ext_vector_type(4))) float float4v;

__device__ __forceinline__ unsigned short f2bf(float f) {
    union { float f; unsigned u; } v; v.f = f;
    unsigned r = v.u + 0x7FFF + ((v.u >> 16) & 1);   // RNE
    return (unsigned short)(r >> 16);
}

// async 16B global->LDS copy (dest = wave-uniform base + lane*16)
__device__ __forceinline__ void gld16(void* lds, const void* g) {
    __builtin_amdgcn_global_load_lds(
        (const __attribute__((address_space(1))) unsigned int*)g,
        (__attribute__((address_space(3))) unsigned int*)lds, 16, 0, 0);
}

__device__ __forceinline__ float fsig(float x)  { return 1.f / (1.f + __expf(-x)); }
__device__ __forceinline__ float ftanh(float x) { return 1.f - 2.f / (__expf(2.f * x) + 1.f); }

// ---------------------------------------------------------------------------
// pack: weights -> bf16.
//  WbfT [256][1024]  (x@W weights, [n][k], 128B-span XOR-preswizzled, for s1)
//  HPbf [256][512]   (h-proj weights, [n][k], preswizzled, for s1)
//        n<64:U0^T | n<96:UU1^T | n<128:0 | n<192:U1^T | n<224:UU0^T | n<256:0
//  BT2  [16 nt][11 s][4 q][4 kc][64 row][8 e]   tile-image for s2 B operand
// ---------------------------------------------------------------------------
__global__ __launch_bounds__(256)
void pack_weights(const float* __restrict__ W,
                  const float* __restrict__ W1, const float* __restrict__ W2,
                  const float* __restrict__ W3, const float* __restrict__ W4,
                  const float* __restrict__ U,  const float* __restrict__ U1,
                  const float* __restrict__ U2, const float* __restrict__ U3,
                  const float* __restrict__ U4,
                  const float* __restrict__ UU, const float* __restrict__ UU1,
                  const float* __restrict__ UU2,const float* __restrict__ UU3,
                  const float* __restrict__ UU4,
                  unsigned short* __restrict__ WbfT,
                  unsigned short* __restrict__ HPbf,
                  unsigned short* __restrict__ BT2)
{
    const float* Wg[4]  = {W1, W2, W3, W4};
    const float* Ug[4]  = {U1, U2, U3, U4};
    const float* UUg[4] = {UU1, UU2, UU3, UU4};
    const long N_WT = 256L * 1024;
    const long N_HP = 256L * 512;
    const long N_BT = 16L * NS2 * 8192;
    const long total = N_WT + N_HP + N_BT;
    for (long t = blockIdx.x * 256L + threadIdx.x; t < total; t += (long)gridDim.x * 256L) {
        if (t < N_WT) {
            int n = (int)(t >> 10), p = (int)(t & 1023);
            int span = p >> 6, slp = (p >> 3) & 7, e = p & 7;
            int k = span * 64 + ((slp ^ (n & 7)) << 3) + e;
            WbfT[t] = f2bf(W[(size_t)k * WRANK + n]);
        } else if (t < N_WT + N_HP) {
            long u = t - N_WT;
            int n = (int)(u >> 9), p = (int)(u & 511);
            int span = p >> 6, slp = (p >> 3) & 7, e = p & 7;
            int k = span * 64 + ((slp ^ (n & 7)) << 3) + e;
            float v;
            if (n < 64)       v = U [(size_t)k * UR0 + n];
            else if (n < 96)  v = UU[(size_t)(HGD + k) * UR1 + (n - 64)];
            else if (n < 128) v = 0.f;
            else if (n < 192) v = U [(size_t)(HGD + k) * UR0 + (n - 128)];
            else if (n < 224) v = UU[(size_t)k * UR1 + (n - 192)];
            else              v = 0.f;
            HPbf[u] = f2bf(v);
        } else {
            long u = t - N_WT - N_HP;
            int img = (int)(u >> 13);            // nt*11 + s
            int nt = img / NS2, s = img % NS2;
            int r = (int)(u & 8191);
            int q = r >> 11, kc = (r >> 9) & 3, row = (r >> 3) & 63, e = r & 7;
            int n = nt * 64 + row, g = n >> 9, nn = n & 511;
            int kk = kc * 8 + e;
            float v;
            if (s < 8)       v = Wg[q][(size_t)(s * 32 + kk) * H_DIM + n];
            else if (s < 10) v = Ug[q][((size_t)g * UR0 + (s - 8) * 32 + kk) * HGD + nn];
            else             v = UUg[q][((size_t)g * UR1 + kk) * HGD + nn];
            BT2[u] = f2bf(v);
        }
    }
}

// ---------------------------------------------------------------------------
// stage 1: A2T = bf16 tile-image of [ x@W | h-projections ]
// BM=64 BN=64 BK=64, 4 waves (wave tile 32x32). B via gld16 (dbuf),
// A reg-prefetched one K-step ahead (fp32->bf16, swizzled ds_write).
// bx 0..3: x@W cols 0..255 ; bx 4..7: h-proj concat cols 256..511
// ---------------------------------------------------------------------------
__global__ __launch_bounds__(256, 4)
void s1_kernel(const float* __restrict__ x, const float* __restrict__ h,
               const unsigned short* __restrict__ WbfT,
               const unsigned short* __restrict__ HPbf,
               unsigned short* __restrict__ A2T)
{
    __shared__ short As[64 * 64];        // 8 KB, single buffer
    __shared__ short Bs[2][64 * 64];     // 2 x 8 KB

    const int flat = blockIdx.x;                  // 1024 blocks
    const int id = (flat & 7) * 128 + (flat >> 3);
    const int bx = id & 7, by = id >> 3;
    const int m0 = by * 64;

    const bool pa = bx < 4;
    const int Kdim = pa ? IN_DIM : HGD;
    const float* Af = pa ? x : h;
    const int a_off = pa ? 0 : ((bx - 4) >> 1) * HGD;
    const unsigned short* Bw = pa ? (WbfT + (size_t)(bx * 64) * IN_DIM)
                                  : (HPbf + (size_t)((bx - 4) * 64) * HGD);
    const int ldbw = pa ? IN_DIM : HGD;
    const int ccol0 = pa ? bx * 64 : WRANK + (bx - 4) * 64;

    const int tid = threadIdx.x, lane = tid & 63, wid = tid >> 6;
    const int wr = wid >> 1, wc = wid & 1;
    const int lr = lane & 15, lh = lane >> 4;
    const int l8 = lane >> 3, l7 = lane & 7;

    f32x4 acc[2][2];
    #pragma unroll
    for (int i = 0; i < 2; ++i)
        #pragma unroll
        for (int j = 0; j < 2; ++j) acc[i][j] = (f32x4){0.f, 0.f, 0.f, 0.f};

    float4v areg[2][2][2];   // [set][chunk][half] -- static indices after unroll

#define S1_STAGEB(buf, kk) do {                                                   \
    _Pragma("unroll")                                                             \
    for (int t = 0; t < 2; ++t) {                                                 \
        int u = wid * 2 + t;                                                      \
        gld16((char*)&Bs[buf][0] + u * 1024,                                      \
              (const char*)Bw + ((size_t)(u * 8 + l8) * ldbw + (kk)) * 2 + l7 * 16); \
    } } while (0)

#define S1_LOADA(set, kk) do {                                                    \
    _Pragma("unroll")                                                             \
    for (int t = 0; t < 2; ++t) {                                                 \
        int cc = tid + t * 256;                                                   \
        int row = cc >> 3, slot = cc & 7;                                         \
        const float* p = Af + (size_t)(m0 + row) * 1024 + a_off + (kk) + slot * 8;\
        areg[set][t][0] = *(const float4v*)p;                                     \
        areg[set][t][1] = *(const float4v*)(p + 4);                               \
    } } while (0)

#define S1_WRITEA(set) do {                                                       \
    _Pragma("unroll")                                                             \
    for (int t = 0; t < 2; ++t) {                                                 \
        int cc = tid + t * 256;                                                   \
        int row = cc >> 3, slot = cc & 7;                                         \
        union { bf16x8 v; unsigned short s_[8]; } uv;                             \
        uv.s_[0] = f2bf(areg[set][t][0].x); uv.s_[1] = f2bf(areg[set][t][0].y);   \
        uv.s_[2] = f2bf(areg[set][t][0].z); uv.s_[3] = f2bf(areg[set][t][0].w);   \
        uv.s_[4] = f2bf(areg[set][t][1].x); uv.s_[5] = f2bf(areg[set][t][1].y);   \
        uv.s_[6] = f2bf(areg[set][t][1].z); uv.s_[7] = f2bf(areg[set][t][1].w);   \
        *(bf16x8*)((char*)As + row * 128 + ((slot ^ (row & 7)) << 4)) = uv.v;     \
    } } while (0)

    S1_STAGEB(0, 0);
    S1_LOADA(0, 0);

    #pragma unroll
    for (int ki = 0; ki < 16; ++ki) {
        if (ki * 64 >= Kdim) break;               // h-path: only 8 steps
        const int cur = ki & 1;
        const bool more = (ki + 1) * 64 < Kdim;
        if (more) S1_STAGEB(cur ^ 1, (ki + 1) * 64);
        if (more) { asm volatile("s_waitcnt vmcnt(2)" ::: "memory"); }
        else      { asm volatile("s_waitcnt vmcnt(0)" ::: "memory"); }
        S1_WRITEA(cur);
        if (more) S1_LOADA(cur ^ 1, (ki + 1) * 64);
        asm volatile("s_waitcnt lgkmcnt(0)" ::: "memory");
        __builtin_amdgcn_s_barrier();
        asm volatile("" ::: "memory");
        #pragma unroll
        for (int ks = 0; ks < 2; ++ks) {
            bf16x8 af[2];
            #pragma unroll
            for (int i = 0; i < 2; ++i) {
                int r = wr * 32 + i * 16 + lr;
                af[i] = *(const bf16x8*)((const char*)As + r * 128
                        + (((ks * 4 + lh) ^ (r & 7)) << 4));
            }
            #pragma unroll
            for (int j = 0; j < 2; ++j) {
                int r = wc * 32 + j * 16 + lr;
                bf16x8 rb = *(const bf16x8*)((const char*)&Bs[cur][0] + r * 128
                            + (((ks * 4 + lh) ^ (r & 7)) << 4));
                #pragma unroll
                for (int i = 0; i < 2; ++i)
                    acc[i][j] = __builtin_amdgcn_mfma_f32_16x16x32_bf16(
                        af[i], rb, acc[i][j], 0, 0, 0);
            }
        }
        asm volatile("" ::: "memory");
        __builtin_amdgcn_s_barrier();
        asm volatile("" ::: "memory");
    }
#undef S1_STAGEB
#undef S1_LOADA
#undef S1_WRITEA

    // epilogue: write A2T tile-image (skip zero-pad columns)
    #pragma unroll
    for (int i = 0; i < 2; ++i) {
        #pragma unroll
        for (int j = 0; j < 2; ++j) {
            int ncol = ccol0 + wc * 32 + j * 16 + lr;    // concat col 0..511
            int blk = ncol >> 5;
            if (blk == 11 || blk == 15) continue;        // pad columns
            int tt = (blk <= 10) ? blk : blk - 1;
            int kk = ncol & 31, kc = kk >> 3, e = kk & 7;
            #pragma unroll
            for (int rr = 0; rr < 4; ++rr) {
                int brow = m0 + wr * 32 + i * 16 + lh * 4 + rr;
                A2T[((size_t)(brow >> 8) * NTA + tt) * 8192 + kc * 2048
                    + (brow & 255) * 8 + e] = f2bf(acc[i][j][rr]);
            }
        }
    }
}

// ---------------------------------------------------------------------------
// stage 2: 4-gate MFMA GEMM (K=352, 11 k-tiles) + LSTM epilogue.
// BM=128 BN=64, 8 waves (2x4), wave tile 64x16 x 4 gates (acc = 64 VGPR).
// LDS 48KB dbuf -> 2 blocks/CU; contiguous gld16 from tile-image A2T/BT2;
// counted vmcnt(3) prefetch pipeline, raw barriers, setprio around MFMA.
// ---------------------------------------------------------------------------
__global__ __launch_bounds__(512, 4)
void s2_kernel(const unsigned short* __restrict__ A2T,
               const unsigned short* __restrict__ BT2,
               const float* __restrict__ bias_f, const float* __restrict__ bias_i,
               const float* __restrict__ bias_c, const float* __restrict__ bias_o,
               const float* __restrict__ cin,
               float* __restrict__ cout, float* __restrict__ hout)
{
    __shared__ short As[2][128 * 32];    // 2 x 8 KB
    __shared__ short Bs[2][4 * 64 * 32]; // 2 x 16 KB

    const int flat = blockIdx.x;                  // 1024 blocks, %8==0 -> bijective
    const int id = (flat & 7) * 128 + (flat >> 3);
    const int nt = id & 15, mt = id >> 4;
    const int m0 = mt * 128, n0 = nt * 64, g = nt >> 3;

    const int tid = threadIdx.x, lane = tid & 63, wid = tid >> 6;
    const int wr = wid >> 2, wc = wid & 3;        // 2 x 4 wave grid
    const int lr = lane & 15, lh = lane >> 4;

    // A2T: panel (mt>>1), half (mt&1); unit u=wid: kc=u>>1, rowblk=u&1
    const char* Abase = (const char*)A2T + (size_t)(mt >> 1) * NTA * 16384
                        + (mt & 1) * 2048 + (wid >> 1) * 4096 + (wid & 1) * 1024
                        + lane * 16;
    const char* Bbase = (const char*)BT2 + (size_t)nt * NS2 * 16384 + lane * 16;

    f32x4 acc[4][4];
    #pragma unroll
    for (int q = 0; q < 4; ++q)
        #pragma unroll
        for (int i = 0; i < 4; ++i) acc[q][i] = (f32x4){0.f, 0.f, 0.f, 0.f};

#define S2_TA(s) ((s) < 8 ? (s) : (g == 0 ? ((s) == 10 ? 13 : (s)) \
                                          : ((s) == 10 ? 10 : (s) + 3)))
#define S2_STAGE(buf, s, tA) do {                                                 \
    gld16((char*)&As[buf][0] + wid * 1024, Abase + (size_t)(tA) * 16384);         \
    _Pragma("unroll")                                                             \
    for (int t = 0; t < 2; ++t) {                                                 \
        int u = wid * 2 + t;                                                      \
        gld16((char*)&Bs[buf][0] + u * 1024,                                      \
              Bbase + (size_t)(s) * 16384 + u * 1024);                            \
    } } while (0)

    S2_STAGE(0, 0, 0);

    #pragma unroll
    for (int s = 0; s < NS2; ++s) {
        const int cur = s & 1;
        if (s < NS2 - 1) {
            const int sn = s + 1;
            const int tA = S2_TA(sn);
            S2_STAGE(cur ^ 1, sn, tA);
            asm volatile("s_waitcnt vmcnt(3)" ::: "memory");  // drain tile s only
        } else {
            asm volatile("s_waitcnt vmcnt(0)" ::: "memory");
        }
        __builtin_amdgcn_s_barrier();
        asm volatile("" ::: "memory");
        __builtin_amdgcn_s_setprio(1);
        {
            bf16x8 af[4];
            #pragma unroll
            for (int i = 0; i < 4; ++i)
                af[i] = *(const bf16x8*)((const char*)&As[cur][0]
                        + lh * 2048 + (wr * 64 + i * 16 + lr) * 16);
            #pragma unroll
            for (int q = 0; q < 4; ++q) {
                bf16x8 rb = *(const bf16x8*)((const char*)&Bs[cur][0]
                            + q * 4096 + lh * 1024 + (wc * 16 + lr) * 16);
                #pragma unroll
                for (int i = 0; i < 4; ++i)
                    acc[q][i] = __builtin_amdgcn_mfma_f32_16x16x32_bf16(
                        af[i], rb, acc[q][i], 0, 0, 0);
            }
        }
        __builtin_amdgcn_s_setprio(0);
        asm volatile("" ::: "memory");
        __builtin_amdgcn_s_barrier();
        asm volatile("" ::: "memory");
    }
#undef S2_STAGE
#undef S2_TA

    // epilogue: gates -> c_next, h_next (each thread owns one column)
    const int ncol = n0 + wc * 16 + lr;
    const float Bi = bias_i[ncol], Bf = bias_f[ncol];
    const float Bo = bias_o[ncol], Bc = bias_c[ncol];
    #pragma unroll
    for (int i = 0; i < 4; ++i) {
        #pragma unroll
        for (int rr = 0; rr < 4; ++rr) {
            int brow = m0 + wr * 64 + i * 16 + lh * 4 + rr;
            float mi = acc[0][i][rr] + Bi;
            float mf = acc[1][i][rr] + Bf;
            float mo = acc[2][i][rr] + Bo;
            float mc = acc[3][i][rr] + Bc;
            float iv = fsig(mi), fv = fsig(mf), ov = fsig(mo);
            float ct = ftanh(mc);
            float cv = cin[(size_t)brow * H_DIM + ncol];
            float cn = fv * cv + iv * ct;
            float hn = ov * ftanh(cn);
            cout[(size_t)brow * H_DIM + ncol] = cn;
            hout[(size_t)brow * H_DIM + ncol] = hn;
        }
    }
}

extern "C" void kernel_launch(void* const* d_in, const int* in_sizes, int n_in,
                              void* d_out, int out_size, void* d_ws, size_t ws_size,
                              hipStream_t stream)
{
    const float* x   = (const float*)d_in[0];
    const float* h   = (const float*)d_in[1];
    const float* c   = (const float*)d_in[2];
    const float* W   = (const float*)d_in[3];
    const float* W1  = (const float*)d_in[4];
    const float* W2  = (const float*)d_in[5];
    const float* W3  = (const float*)d_in[6];
    const float* W4  = (const float*)d_in[7];
    const float* U   = (const float*)d_in[8];
    const float* U1  = (const float*)d_in[9];
    const float* U2  = (const float*)d_in[10];
    const float* U3  = (const float*)d_in[11];
    const float* U4  = (const float*)d_in[12];
    const float* UU  = (const float*)d_in[13];
    const float* UU1 = (const float*)d_in[14];
    const float* UU2 = (const float*)d_in[15];
    const float* UU3 = (const float*)d_in[16];
    const float* UU4 = (const float*)d_in[17];
    const float* bias_f = (const float*)d_in[18];   // dict order: f, i, c, o
    const float* bias_i = (const float*)d_in[19];
    const float* bias_c = (const float*)d_in[20];
    const float* bias_o = (const float*)d_in[21];

    unsigned short* A2T  = (unsigned short*)d_ws;            // 32*14*8192 = 3,670,016
    unsigned short* WbfT = A2T  + 32L * NTA * 8192;          // 262,144
    unsigned short* HPbf = WbfT + 256L * 1024;               // 131,072
    unsigned short* BT2  = HPbf + 256L * 512;                // 16*11*8192 = 1,441,792

    float* c_out = (float*)d_out;
    float* h_out = c_out + (size_t)B_ROWS * H_DIM;

    pack_weights<<<dim3(2048), dim3(256), 0, stream>>>(
        W, W1, W2, W3, W4, U, U1, U2, U3, U4, UU, UU1, UU2, UU3, UU4,
        WbfT, HPbf, BT2);

    s1_kernel<<<dim3(1024), dim3(256), 0, stream>>>(x, h, WbfT, HPbf, A2T);

    s2_kernel<<<dim3(1024), dim3(512), 0, stream>>>(
        A2T, BT2, bias_f, bias_i, bias_c, bias_o, c, c_out, h_out);
}